// Round 1
// baseline (370.451 us; speedup 1.0000x reference)
//
#include <hip/hip_runtime.h>
#include <math.h>

// Flip to 0 if absmax lands in the ~1..11 range (wrong jax threefry variant).
#ifndef JAX_PARTITIONABLE
#define JAX_PARTITIONABLE 1
#endif

#define NB 32
#define NC 33
#define HWDIM 256
#define NPATCH 36
#define FEAT 107
#define CROP_ELEMS 2112  // 33*8*8

__device__ __constant__ float c_SHX[9] = {
  -8.0f/255.0f, -8.0f/255.0f, 0.0f, 8.0f/255.0f, 8.0f/255.0f,
   8.0f/255.0f, 0.0f, -8.0f/255.0f, 0.0f };
__device__ __constant__ float c_SHY[9] = {
   0.0f, 8.0f/255.0f, 8.0f/255.0f, 8.0f/255.0f, 0.0f,
  -8.0f/255.0f, 8.0f/255.0f, -8.0f/255.0f, 0.0f };

// Faithful replay of the reference's sequential in-place lh updates
// (including the idx = i*j indexing bug). clx/cly get the 36 crop landmarks
// in crop order; lh gets the final 36x2 state.
__device__ inline void simulate_lh(const float* xb, float* clx, float* cly,
                                   float* lh /*36*2*/) {
  float lx[36], ly[36];
  for (int n = 0; n < 36; ++n) { lx[n] = xb[(n/9)*2]; ly[n] = xb[(n/9)*2+1]; }
  int c = 0;
  for (int i = 0; i < 4; ++i)
    for (int j = 0; j < 9; ++j) {
      int idx = i * j;
      lx[idx] += c_SHX[j];
      ly[idx] += c_SHY[j];
      clx[c] = lx[idx]; cly[c] = ly[idx]; ++c;
    }
  for (int n = 0; n < 36; ++n) { lh[n*2] = lx[n]; lh[n*2+1] = ly[n]; }
}

// ---------------- Kernel 1: crops + full 8x8 "conv" contraction ------------
__global__ __launch_bounds__(256) void patch_feat_kernel(
    const float* __restrict__ d, const float* __restrict__ x,
    const float* __restrict__ conv_w, const float* __restrict__ conv_b,
    float* __restrict__ pf) {
  const int b = blockIdx.x;
  const int n = blockIdx.y;
  __shared__ float s_crop[CROP_ELEMS];
  __shared__ float s_land[2];
  if (threadIdx.x == 0) {
    float clx[36], cly[36], lh[72];
    simulate_lh(x + b * 8, clx, cly, lh);
    s_land[0] = clx[n]; s_land[1] = cly[n];
  }
  __syncthreads();
  const float lxv = s_land[0], lyv = s_land[1];
  int ix = (int)rintf(lxv * 255.0f);            // jnp.round = half-to-even
  ix = ix < 0 ? 0 : (ix > 255 ? 255 : ix);
  int iy = (int)rintf((lyv + 1.0f) * 255.0f);
  iy = iy < 0 ? 0 : (iy > 255 ? 255 : iy);
  const float* db = d + (size_t)b * NC * HWDIM * HWDIM;
  for (int k = threadIdx.x; k < CROP_ELEMS; k += 256) {
    int c = k >> 6;
    int u = (k >> 3) & 7;
    int v = k & 7;
    int r = ix + u - 4;     // padded crop -> original row/col, 0 outside
    int col = iy + v - 4;
    float val = 0.0f;
    if (r >= 0 && r < HWDIM && col >= 0 && col < HWDIM)
      val = db[(c * HWDIM + r) * HWDIM + col];
    s_crop[k] = val;
  }
  __syncthreads();
  const int wave = threadIdx.x >> 6;
  const int lane = threadIdx.x & 63;
  for (int o = wave; o < NC; o += 4) {
    const float* w = conv_w + o * CROP_ELEMS;
    float acc = 0.0f;
    #pragma unroll
    for (int k = 0; k < 33; ++k) {              // 2112 = 64 lanes * 33
      int e = lane + (k << 6);
      acc += s_crop[e] * w[e];
    }
    #pragma unroll
    for (int off = 32; off > 0; off >>= 1)
      acc += __shfl_xor(acc, off, 64);
    if (lane == 0) pf[(b * NPATCH + n) * NC + o] = acc + conv_b[o];
  }
}

// ---------------- Threefry-2x32 (matches jax/_src/prng.py) -----------------
__device__ inline void tf2x32(unsigned k0, unsigned k1, unsigned x0, unsigned x1,
                              unsigned& o0, unsigned& o1) {
  unsigned ks2 = k0 ^ k1 ^ 0x1BD11BDAu;
#define TFR(r) { x0 += x1; x1 = (x1 << r) | (x1 >> (32 - r)); x1 ^= x0; }
  x0 += k0; x1 += k1;
  TFR(13) TFR(15) TFR(26) TFR(6)
  x0 += k1;  x1 += ks2 + 1u;
  TFR(17) TFR(29) TFR(16) TFR(24)
  x0 += ks2; x1 += k0 + 2u;
  TFR(13) TFR(15) TFR(26) TFR(6)
  x0 += k0;  x1 += k1 + 3u;
  TFR(17) TFR(29) TFR(16) TFR(24)
  x0 += k1;  x1 += ks2 + 4u;
  TFR(13) TFR(15) TFR(26) TFR(6)
  x0 += ks2; x1 += k0 + 5u;
#undef TFR
  o0 = x0; o1 = x1;
}

// bernoulli(p=0.9) mask bit for flat index idx of a (32,4,107) draw.
__device__ inline float drop_mask(unsigned ka, unsigned kb, unsigned idx) {
#if JAX_PARTITIONABLE
  unsigned b0, b1;
  tf2x32(ka, kb, 0u, idx, b0, b1);     // 64-bit iota: hi=0, lo=idx
  unsigned bits = b0 ^ b1;
#else
  const unsigned half = 6848u;         // (32*4*107)/2
  unsigned ln = idx < half ? idx : idx - half;
  unsigned b0, b1;
  tf2x32(ka, kb, ln, ln + half, b0, b1);
  unsigned bits = idx < half ? b0 : b1;
#endif
  float u = __uint_as_float((bits >> 9) | 0x3F800000u) - 1.0f;
  return u < 0.9f ? 1.0f : 0.0f;
}

// ---------------- Kernel 2: hypergraph message + head ----------------------
__global__ __launch_bounds__(64) void head_kernel(
    const float* __restrict__ x, const float* __restrict__ H,
    const float* __restrict__ T, const float* __restrict__ W,
    const float* __restrict__ lin1w, const float* __restrict__ lin1b,
    const float* __restrict__ lin2w, const float* __restrict__ lin2b,
    const float* __restrict__ pf, float* __restrict__ out) {
  const int b = blockIdx.x >> 2;
  const int p = blockIdx.x & 3;
  const int lane = threadIdx.x;
  __shared__ float s_lh[72];
  __shared__ float s_A[16];
  __shared__ float s_M1[36];
  if (lane == 0) {
    float clx[36], cly[36];
    simulate_lh(x + b * 8, clx, cly, s_lh);
  }
  __syncthreads();
  if (lane < 16) {                       // A = T[p,:] @ (H * W)
    float a = 0.0f;
    for (int k = 0; k < 36; ++k)
      a += T[p * 36 + k] * (H[k * 16 + lane] * W[lane]);
    s_A[lane] = a;
  }
  __syncthreads();
  if (lane < 36) {                       // M1[p,n] = A @ H[n,:]
    float m = 0.0f;
    for (int h = 0; h < 16; ++h) m += s_A[h] * H[lane * 16 + h];
    s_M1[lane] = m;
  }
  __syncthreads();

  const int f0 = lane;
  const int f1 = lane + 64;
  const bool has1 = (f1 < FEAT);
  float msg0 = 0.0f, msg1 = 0.0f;
  const float* pfb = pf + b * NPATCH * NC;
  for (int n = 0; n < 36; ++n) {
    float m1v = s_M1[n];
    float g0;
    if (f0 < 33) g0 = pfb[n * 33 + f0];
    else if (f0 < 105) {
      int q = f0 - 33; int mm = q >> 1, cc = q & 1;
      g0 = s_lh[mm * 2 + cc] - s_lh[n * 2 + cc];
    } else g0 = s_lh[n * 2 + (f0 - 105)];
    msg0 += m1v * g0;
    if (has1) {
      float g1;
      if (f1 < 105) {
        int q = f1 - 33; int mm = q >> 1, cc = q & 1;
        g1 = s_lh[mm * 2 + cc] - s_lh[n * 2 + cc];
      } else g1 = s_lh[n * 2 + (f1 - 105)];
      msg1 += m1v * g1;
    }
  }

  // keys from jax.random.split(jax.random.key(42))
  unsigned k1a, k1b, k2a, k2b;
#if JAX_PARTITIONABLE
  tf2x32(0u, 42u, 0u, 0u, k1a, k1b);
  tf2x32(0u, 42u, 0u, 1u, k2a, k2b);
#else
  { unsigned a0, c0, a1, c1;
    tf2x32(0u, 42u, 0u, 2u, a0, c0);   // lanes (0,2) and (1,3) of iota(4)
    tf2x32(0u, 42u, 1u, 3u, a1, c1);
    k1a = a0; k1b = a1; k2a = c0; k2b = c1; }
#endif
  unsigned base = (unsigned)((b * 4 + p) * FEAT);
  float x1_0 = msg0 * drop_mask(k1a, k1b, base + f0) / 0.9f;
  float x2_0 = msg0 * drop_mask(k2a, k2b, base + f0) / 0.9f;
  float x1_1 = 0.0f, x2_1 = 0.0f;
  if (has1) {
    x1_1 = msg1 * drop_mask(k1a, k1b, base + f1) / 0.9f;
    x2_1 = msg1 * drop_mask(k2a, k2b, base + f1) / 0.9f;
  }

  float r[11];
  #pragma unroll
  for (int k = 0; k < 2; ++k) {
    float v = x1_0 * lin1w[k * FEAT + f0];
    if (has1) v += x1_1 * lin1w[k * FEAT + f1];
    r[k] = v;
  }
  #pragma unroll
  for (int j = 0; j < 9; ++j) {
    float v = x2_0 * lin2w[j * FEAT + f0];
    if (has1) v += x2_1 * lin2w[j * FEAT + f1];
    r[2 + j] = v;
  }
  #pragma unroll
  for (int off = 32; off > 0; off >>= 1) {
    #pragma unroll
    for (int k = 0; k < 11; ++k) r[k] += __shfl_xor(r[k], off, 64);
  }
  if (lane == 0) {
    float o0 = 1.0f / (1.0f + expf(-(r[0] + lin1b[0])));
    float o1 = 1.0f / (1.0f + expf(-(r[1] + lin1b[1])));
    float lg[9], mx = -1e30f;
    for (int j = 0; j < 9; ++j) { lg[j] = r[2 + j] + lin2b[j]; if (lg[j] > mx) mx = lg[j]; }
    float s = 0.0f;
    for (int j = 0; j < 9; ++j) { lg[j] = expf(lg[j] - mx); s += lg[j]; }
    float sx = 0.0f, sy = 0.0f;
    for (int j = 0; j < 9; ++j) {
      float dj = lg[j] / s;
      sx += dj * c_SHX[j];
      sy += dj * c_SHY[j];
    }
    int o = (b * 4 + p) * 2;
    out[o + 0] = (x[b * 8 + p * 2 + 0] + o0 * sx) * 255.0f;
    out[o + 1] = (x[b * 8 + p * 2 + 1] + o1 * sy) * 255.0f;
  }
}

extern "C" void kernel_launch(void* const* d_in, const int* in_sizes, int n_in,
                              void* d_out, int out_size, void* d_ws, size_t ws_size,
                              hipStream_t stream) {
  const float* d     = (const float*)d_in[0];
  const float* x     = (const float*)d_in[1];
  const float* convw = (const float*)d_in[2];
  const float* convb = (const float*)d_in[3];
  const float* H     = (const float*)d_in[4];
  const float* T     = (const float*)d_in[5];
  const float* W     = (const float*)d_in[6];
  const float* l1w   = (const float*)d_in[7];
  const float* l1b   = (const float*)d_in[8];
  const float* l2w   = (const float*)d_in[9];
  const float* l2b   = (const float*)d_in[10];
  float* out = (float*)d_out;
  float* pf  = (float*)d_ws;  // 32*36*33 floats = 152 KB scratch

  dim3 g1(NB, NPATCH);
  patch_feat_kernel<<<g1, 256, 0, stream>>>(d, x, convw, convb, pf);
  head_kernel<<<NB * 4, 64, 0, stream>>>(x, H, T, W, l1w, l1b, l2w, l2b, pf, out);
}

// Round 2
// 356.825 us; speedup vs baseline: 1.0382x; 1.0382x over previous
//
#include <hip/hip_runtime.h>
#include <math.h>

#define NB 32
#define NC 33
#define HWDIM 256
#define NPATCH 36
#define FEAT 107
#define CROP_ELEMS 2112  // 33*8*8
#define CPB 2            // crops per block in kernel 1

__device__ __constant__ float c_SHX[9] = {
  -8.0f/255.0f, -8.0f/255.0f, 0.0f, 8.0f/255.0f, 8.0f/255.0f,
   8.0f/255.0f, 0.0f, -8.0f/255.0f, 0.0f };
__device__ __constant__ float c_SHY[9] = {
   0.0f, 8.0f/255.0f, 8.0f/255.0f, 8.0f/255.0f, 0.0f,
  -8.0f/255.0f, 8.0f/255.0f, -8.0f/255.0f, 0.0f };

// Compile-time replay of the reference's sequential in-place lh updates
// (incl. the idx = i*j bug). For each crop c we record the exact ordered list
// of shift indices applied to its slot up to and including step c; padded
// with index 8 whose shift is exactly (0,0) -> fp32 no-op, so the add chain
// is bitwise identical to the reference's sequential accumulation.
struct Tables {
  int pt[36];        // crop c -> source point
  int ch[36][12];    // crop c -> ordered shift-index chain (padded with 8)
  int ptS[36];       // slot s -> source point (final lh state)
  int chS[36][12];   // slot s -> full ordered chain (padded with 8)
};
constexpr Tables make_tables() {
  Tables t = {};
  int hits[36][12] = {};
  int nh[36] = {};
  int c = 0;
  for (int i = 0; i < 4; ++i)
    for (int j = 0; j < 9; ++j) {
      int idx = i * j;
      hits[idx][nh[idx]] = j; nh[idx]++;
      t.pt[c] = idx / 9;
      for (int k = 0; k < 12; ++k) t.ch[c][k] = (k < nh[idx]) ? hits[idx][k] : 8;
      ++c;
    }
  for (int s = 0; s < 36; ++s) {
    t.ptS[s] = s / 9;
    for (int k = 0; k < 12; ++k) t.chS[s][k] = (k < nh[s]) ? hits[s][k] : 8;
  }
  return t;
}
__device__ __constant__ Tables c_tab = make_tables();

// ---------------- Kernel 1: crops + full 8x8 "conv" contraction ------------
__global__ __launch_bounds__(256) void patch_feat_kernel(
    const float* __restrict__ d, const float* __restrict__ x,
    const float* __restrict__ conv_w, const float* __restrict__ conv_b,
    float* __restrict__ pf) {
  const int b = blockIdx.x;
  const int n0 = blockIdx.y * CPB;
  __shared__ float s_crop[CPB][CROP_ELEMS];

  const float* db = d + (size_t)b * NC * HWDIM * HWDIM;
  #pragma unroll
  for (int cc = 0; cc < CPB; ++cc) {
    const int n = n0 + cc;
    float lx = x[b * 8 + c_tab.pt[n] * 2 + 0];
    float ly = x[b * 8 + c_tab.pt[n] * 2 + 1];
    #pragma unroll
    for (int t = 0; t < 12; ++t) {
      int j = c_tab.ch[n][t];
      lx += c_SHX[j]; ly += c_SHY[j];
    }
    int ix = (int)rintf(lx * 255.0f);            // jnp.round = half-to-even
    ix = ix < 0 ? 0 : (ix > 255 ? 255 : ix);
    int iy = (int)rintf((ly + 1.0f) * 255.0f);
    iy = iy < 0 ? 0 : (iy > 255 ? 255 : iy);
    for (int k = threadIdx.x; k < CROP_ELEMS; k += 256) {
      int c = k >> 6;
      int u = (k >> 3) & 7;
      int v = k & 7;
      int r = ix + u - 4;
      int col = iy + v - 4;
      float val = 0.0f;
      if (r >= 0 && r < HWDIM && col >= 0 && col < HWDIM)
        val = db[(c * HWDIM + r) * HWDIM + col];
      s_crop[cc][k] = val;
    }
  }
  __syncthreads();

  const int wave = threadIdx.x >> 6;
  const int lane = threadIdx.x & 63;
  // Load both crops into registers: 8 float4 + 1 tail float per crop per lane.
  float4 cr[CPB][8];
  float ct[CPB];
  #pragma unroll
  for (int cc = 0; cc < CPB; ++cc) {
    #pragma unroll
    for (int k = 0; k < 8; ++k)
      cr[cc][k] = *(const float4*)&s_crop[cc][k * 256 + lane * 4];
    ct[cc] = s_crop[cc][2048 + lane];
  }
  // channels: wave0 -> 0..8, wave1 -> 9..16, wave2 -> 17..24, wave3 -> 25..32
  const int obeg = (wave == 0) ? 0 : (9 + (wave - 1) * 8);
  const int ocnt = (wave == 0) ? 9 : 8;
  for (int oi = 0; oi < ocnt; ++oi) {
    const int o = obeg + oi;
    const float* w = conv_w + o * CROP_ELEMS;
    float acc[CPB];
    #pragma unroll
    for (int cc = 0; cc < CPB; ++cc) acc[cc] = 0.0f;
    #pragma unroll
    for (int k = 0; k < 8; ++k) {
      float4 wv = *(const float4*)&w[k * 256 + lane * 4];
      #pragma unroll
      for (int cc = 0; cc < CPB; ++cc) {
        acc[cc] += wv.x * cr[cc][k].x + wv.y * cr[cc][k].y +
                   wv.z * cr[cc][k].z + wv.w * cr[cc][k].w;
      }
    }
    float wt = w[2048 + lane];
    #pragma unroll
    for (int cc = 0; cc < CPB; ++cc) acc[cc] += wt * ct[cc];
    #pragma unroll
    for (int off = 32; off > 0; off >>= 1) {
      #pragma unroll
      for (int cc = 0; cc < CPB; ++cc)
        acc[cc] += __shfl_xor(acc[cc], off, 64);
    }
    if (lane == 0) {
      #pragma unroll
      for (int cc = 0; cc < CPB; ++cc)
        pf[(b * NPATCH + n0 + cc) * NC + o] = acc[cc] + conv_b[o];
    }
  }
}

// ---------------- Threefry-2x32 (matches jax/_src/prng.py) -----------------
__device__ inline void tf2x32(unsigned k0, unsigned k1, unsigned x0, unsigned x1,
                              unsigned& o0, unsigned& o1) {
  unsigned ks2 = k0 ^ k1 ^ 0x1BD11BDAu;
#define TFR(r) { x0 += x1; x1 = (x1 << r) | (x1 >> (32 - r)); x1 ^= x0; }
  x0 += k0; x1 += k1;
  TFR(13) TFR(15) TFR(26) TFR(6)
  x0 += k1;  x1 += ks2 + 1u;
  TFR(17) TFR(29) TFR(16) TFR(24)
  x0 += ks2; x1 += k0 + 2u;
  TFR(13) TFR(15) TFR(26) TFR(6)
  x0 += k0;  x1 += k1 + 3u;
  TFR(17) TFR(29) TFR(16) TFR(24)
  x0 += k1;  x1 += ks2 + 4u;
  TFR(13) TFR(15) TFR(26) TFR(6)
  x0 += ks2; x1 += k0 + 5u;
#undef TFR
  o0 = x0; o1 = x1;
}

__device__ inline float drop_mask(unsigned ka, unsigned kb, unsigned idx) {
  unsigned b0, b1;
  tf2x32(ka, kb, 0u, idx, b0, b1);     // partitionable threefry: 64-bit iota
  unsigned bits = b0 ^ b1;
  float u = __uint_as_float((bits >> 9) | 0x3F800000u) - 1.0f;
  return u < 0.9f ? 1.0f : 0.0f;
}

// ---------------- Kernel 2: hypergraph message + head ----------------------
__global__ __launch_bounds__(64) void head_kernel(
    const float* __restrict__ x, const float* __restrict__ H,
    const float* __restrict__ T, const float* __restrict__ W,
    const float* __restrict__ lin1w, const float* __restrict__ lin1b,
    const float* __restrict__ lin2w, const float* __restrict__ lin2b,
    const float* __restrict__ pf, float* __restrict__ out) {
  const int b = blockIdx.x >> 2;
  const int p = blockIdx.x & 3;
  const int lane = threadIdx.x;
  __shared__ float s_lh[72];
  __shared__ float s_A[16];
  __shared__ float s_M1[36];
  if (lane < 36) {                       // final lh state, exact chains
    float vx = x[b * 8 + c_tab.ptS[lane] * 2 + 0];
    float vy = x[b * 8 + c_tab.ptS[lane] * 2 + 1];
    #pragma unroll
    for (int t = 0; t < 12; ++t) {
      int j = c_tab.chS[lane][t];
      vx += c_SHX[j]; vy += c_SHY[j];
    }
    s_lh[lane * 2 + 0] = vx;
    s_lh[lane * 2 + 1] = vy;
  }
  __syncthreads();
  if (lane < 16) {                       // A = T[p,:] @ (H * W)
    float a = 0.0f;
    for (int k = 0; k < 36; ++k)
      a += T[p * 36 + k] * (H[k * 16 + lane] * W[lane]);
    s_A[lane] = a;
  }
  __syncthreads();
  if (lane < 36) {                       // M1[p,n] = A @ H[n,:]
    float m = 0.0f;
    for (int h = 0; h < 16; ++h) m += s_A[h] * H[lane * 16 + h];
    s_M1[lane] = m;
  }
  __syncthreads();

  const int f0 = lane;
  const int f1 = lane + 64;
  const bool has1 = (f1 < FEAT);
  float msg0 = 0.0f, msg1 = 0.0f;
  const float* pfb = pf + b * NPATCH * NC;
  for (int n = 0; n < 36; ++n) {
    float m1v = s_M1[n];
    float g0;
    if (f0 < 33) g0 = pfb[n * 33 + f0];
    else if (f0 < 105) {
      int q = f0 - 33; int mm = q >> 1, cc = q & 1;
      g0 = s_lh[mm * 2 + cc] - s_lh[n * 2 + cc];
    } else g0 = s_lh[n * 2 + (f0 - 105)];
    msg0 += m1v * g0;
    if (has1) {
      float g1;
      if (f1 < 105) {
        int q = f1 - 33; int mm = q >> 1, cc = q & 1;
        g1 = s_lh[mm * 2 + cc] - s_lh[n * 2 + cc];
      } else g1 = s_lh[n * 2 + (f1 - 105)];
      msg1 += m1v * g1;
    }
  }

  unsigned k1a, k1b, k2a, k2b;
  tf2x32(0u, 42u, 0u, 0u, k1a, k1b);   // jax.random.split(key(42))[0]
  tf2x32(0u, 42u, 0u, 1u, k2a, k2b);   // jax.random.split(key(42))[1]
  unsigned base = (unsigned)((b * 4 + p) * FEAT);
  float x1_0 = msg0 * drop_mask(k1a, k1b, base + f0) / 0.9f;
  float x2_0 = msg0 * drop_mask(k2a, k2b, base + f0) / 0.9f;
  float x1_1 = 0.0f, x2_1 = 0.0f;
  if (has1) {
    x1_1 = msg1 * drop_mask(k1a, k1b, base + f1) / 0.9f;
    x2_1 = msg1 * drop_mask(k2a, k2b, base + f1) / 0.9f;
  }

  float r[11];
  #pragma unroll
  for (int k = 0; k < 2; ++k) {
    float v = x1_0 * lin1w[k * FEAT + f0];
    if (has1) v += x1_1 * lin1w[k * FEAT + f1];
    r[k] = v;
  }
  #pragma unroll
  for (int j = 0; j < 9; ++j) {
    float v = x2_0 * lin2w[j * FEAT + f0];
    if (has1) v += x2_1 * lin2w[j * FEAT + f1];
    r[2 + j] = v;
  }
  #pragma unroll
  for (int off = 32; off > 0; off >>= 1) {
    #pragma unroll
    for (int k = 0; k < 11; ++k) r[k] += __shfl_xor(r[k], off, 64);
  }
  if (lane == 0) {
    float o0 = 1.0f / (1.0f + expf(-(r[0] + lin1b[0])));
    float o1 = 1.0f / (1.0f + expf(-(r[1] + lin1b[1])));
    float lg[9], mx = -1e30f;
    for (int j = 0; j < 9; ++j) { lg[j] = r[2 + j] + lin2b[j]; if (lg[j] > mx) mx = lg[j]; }
    float s = 0.0f;
    for (int j = 0; j < 9; ++j) { lg[j] = expf(lg[j] - mx); s += lg[j]; }
    float sx = 0.0f, sy = 0.0f;
    for (int j = 0; j < 9; ++j) {
      float dj = lg[j] / s;
      sx += dj * c_SHX[j];
      sy += dj * c_SHY[j];
    }
    int o = (b * 4 + p) * 2;
    out[o + 0] = (x[b * 8 + p * 2 + 0] + o0 * sx) * 255.0f;
    out[o + 1] = (x[b * 8 + p * 2 + 1] + o1 * sy) * 255.0f;
  }
}

extern "C" void kernel_launch(void* const* d_in, const int* in_sizes, int n_in,
                              void* d_out, int out_size, void* d_ws, size_t ws_size,
                              hipStream_t stream) {
  const float* d     = (const float*)d_in[0];
  const float* x     = (const float*)d_in[1];
  const float* convw = (const float*)d_in[2];
  const float* convb = (const float*)d_in[3];
  const float* H     = (const float*)d_in[4];
  const float* T     = (const float*)d_in[5];
  const float* W     = (const float*)d_in[6];
  const float* l1w   = (const float*)d_in[7];
  const float* l1b   = (const float*)d_in[8];
  const float* l2w   = (const float*)d_in[9];
  const float* l2b   = (const float*)d_in[10];
  float* out = (float*)d_out;
  float* pf  = (float*)d_ws;  // 32*36*33 floats = 152 KB scratch

  dim3 g1(NB, NPATCH / CPB);
  patch_feat_kernel<<<g1, 256, 0, stream>>>(d, x, convw, convb, pf);
  head_kernel<<<NB * 4, 64, 0, stream>>>(x, H, T, W, l1w, l1b, l2w, l2b, pf, out);
}